// Round 1
// baseline (536.989 us; speedup 1.0000x reference)
//
#include <hip/hip_runtime.h>
#include <hip/hip_bf16.h>
#include <cstdint>

#define NNODES 100000
#define NEDGES 1000000
#define HDIM 64
#define ODIM 16
#define NB 8
#define KDIM (HDIM * NB)   // 512 = GEMM inner dim, k = i*8 + b
#define TILE 64

typedef short short8 __attribute__((ext_vector_type(8)));
typedef float f32x4  __attribute__((ext_vector_type(4)));
union FragU { uint4 u; short8 s; };

__device__ __forceinline__ float asf(uint32_t u) { float f; __builtin_memcpy(&f, &u, 4); return f; }
__device__ __forceinline__ uint32_t asu(float f) { uint32_t u; __builtin_memcpy(&u, &f, 4); return u; }
__device__ __forceinline__ uint16_t f2bf(float f) {
    uint32_t x = asu(f);
    return (uint16_t)((x + 0x7FFFu + ((x >> 16) & 1u)) >> 16);
}
__device__ __forceinline__ uint32_t pack2(float lo, float hi) {
    return (uint32_t)f2bf(lo) | ((uint32_t)f2bf(hi) << 16);
}
__device__ __forceinline__ void fmaC(const float4& cA, const float4& cB, float xs,
                                     float* __restrict__ acc) {
    acc[0] = fmaf(cA.x, xs, acc[0]); acc[1] = fmaf(cA.y, xs, acc[1]);
    acc[2] = fmaf(cA.z, xs, acc[2]); acc[3] = fmaf(cA.w, xs, acc[3]);
    acc[4] = fmaf(cB.x, xs, acc[4]); acc[5] = fmaf(cB.y, xs, acc[5]);
    acc[6] = fmaf(cB.z, xs, acc[6]); acc[7] = fmaf(cB.w, xs, acc[7]);
}

// ---------------------------------------------------------------------------
// cast: f32 feats -> bf16 x  (4 elems/thread)
// ---------------------------------------------------------------------------
__global__ void cast_kernel(const float* __restrict__ in, uint16_t* __restrict__ out, int n4) {
    const int stride = (int)(gridDim.x * blockDim.x);
    for (int idx = (int)(blockIdx.x * blockDim.x + threadIdx.x); idx < n4; idx += stride) {
        float4 v = reinterpret_cast<const float4*>(in)[idx];
        uint2 p;
        p.x = pack2(v.x, v.y);
        p.y = pack2(v.z, v.w);
        reinterpret_cast<uint2*>(out)[idx] = p;
    }
}

// ---------------------------------------------------------------------------
// CSR build: histogram by dst -> exclusive scan -> scatter packed edge recs
// rec[e] = { src | (etype<<20), norm }  (8 B)
// ---------------------------------------------------------------------------
__global__ void zero_kernel(int* __restrict__ p, int n) {
    for (int i = (int)(blockIdx.x * blockDim.x + threadIdx.x); i < n;
         i += (int)(gridDim.x * blockDim.x)) p[i] = 0;
}

__global__ void hist_kernel(const int* __restrict__ dst, int* __restrict__ cnt, int nE) {
    for (int e = (int)(blockIdx.x * blockDim.x + threadIdx.x); e < nE;
         e += (int)(gridDim.x * blockDim.x)) atomicAdd(&cnt[dst[e]], 1);
}

#define SCAN_B 512
__launch_bounds__(SCAN_B)
__global__ void scan_partial_kernel(const int* __restrict__ cnt, int* __restrict__ bsum, int n) {
    __shared__ int sh[SCAN_B];
    int id = (int)(blockIdx.x * SCAN_B + threadIdx.x);
    sh[threadIdx.x] = (id < n) ? cnt[id] : 0;
    __syncthreads();
    for (int off = SCAN_B / 2; off > 0; off >>= 1) {
        if ((int)threadIdx.x < off) sh[threadIdx.x] += sh[threadIdx.x + off];
        __syncthreads();
    }
    if (threadIdx.x == 0) bsum[blockIdx.x] = sh[0];
}

__launch_bounds__(256)
__global__ void scan_base_kernel(const int* __restrict__ bsum, int* __restrict__ bbase,
                                 int* __restrict__ offs, int nblk, int nNodes) {
    __shared__ int sh[256];
    const int t = (int)threadIdx.x;
    int v = (t < nblk) ? bsum[t] : 0;
    sh[t] = v;
    __syncthreads();
    for (int off = 1; off < 256; off <<= 1) {
        int tmp = (t >= off) ? sh[t - off] : 0;
        __syncthreads();
        sh[t] += tmp;
        __syncthreads();
    }
    if (t < nblk) bbase[t] = sh[t] - v;       // exclusive base per block
    if (t == 255) offs[nNodes] = sh[255];     // grand total
}

__launch_bounds__(SCAN_B)
__global__ void scan_final_kernel(int* __restrict__ cnt, const int* __restrict__ bbase,
                                  int* __restrict__ offs, int n) {
    __shared__ int sh[SCAN_B];
    int id = (int)(blockIdx.x * SCAN_B + threadIdx.x);
    int v = (id < n) ? cnt[id] : 0;
    sh[threadIdx.x] = v;
    __syncthreads();
    for (int off = 1; off < SCAN_B; off <<= 1) {
        int tmp = ((int)threadIdx.x >= off) ? sh[threadIdx.x - off] : 0;
        __syncthreads();
        sh[threadIdx.x] += tmp;
        __syncthreads();
    }
    if (id < n) {
        int excl = sh[threadIdx.x] - v + bbase[blockIdx.x];
        offs[id] = excl;
        cnt[id]  = excl;   // becomes the scatter cursor
    }
}

__global__ void scatter_kernel(const int* __restrict__ src, const int* __restrict__ dst,
                               const int* __restrict__ et, const float* __restrict__ norm,
                               int* __restrict__ cursor, uint2* __restrict__ rec, int nE) {
    for (int e = (int)(blockIdx.x * blockDim.x + threadIdx.x); e < nE;
         e += (int)(gridDim.x * blockDim.x)) {
        int p = atomicAdd(&cursor[dst[e]], 1);
        rec[p] = make_uint2((uint32_t)src[e] | ((uint32_t)et[e] << 20), asu(norm[e]));
    }
}

// ---------------------------------------------------------------------------
// Gather for one dst node (verbatim math/order from the proven csr_agg):
// half-wave lane hl accumulates i=2hl (accL) and i=2hl+1 (accH) over bases.
// ---------------------------------------------------------------------------
__device__ __forceinline__ void gather_node(const uint16_t* __restrict__ x,
                                            const float* __restrict__ coeff,
                                            const uint2* __restrict__ rec,
                                            int j0, int j1, int hl,
                                            float* __restrict__ accL,
                                            float* __restrict__ accH) {
    int j = j0;
    for (; j + 4 <= j1; j += 4) {
        const uint2 r0 = rec[j];
        const uint2 r1 = rec[j + 1];
        const uint2 r2 = rec[j + 2];
        const uint2 r3 = rec[j + 3];
        const uint32_t w0 = *reinterpret_cast<const uint32_t*>(
            x + (size_t)(r0.x & 0xFFFFFu) * HDIM + 2 * hl);
        const uint32_t w1 = *reinterpret_cast<const uint32_t*>(
            x + (size_t)(r1.x & 0xFFFFFu) * HDIM + 2 * hl);
        const uint32_t w2 = *reinterpret_cast<const uint32_t*>(
            x + (size_t)(r2.x & 0xFFFFFu) * HDIM + 2 * hl);
        const uint32_t w3 = *reinterpret_cast<const uint32_t*>(
            x + (size_t)(r3.x & 0xFFFFFu) * HDIM + 2 * hl);
        {
            const float4 cA = *reinterpret_cast<const float4*>(coeff + (r0.x >> 20) * NB);
            const float4 cB = *reinterpret_cast<const float4*>(coeff + (r0.x >> 20) * NB + 4);
            const float nm = asf(r0.y);
            fmaC(cA, cB, asf(w0 << 16) * nm, accL);
            fmaC(cA, cB, asf(w0 & 0xFFFF0000u) * nm, accH);
        }
        {
            const float4 cA = *reinterpret_cast<const float4*>(coeff + (r1.x >> 20) * NB);
            const float4 cB = *reinterpret_cast<const float4*>(coeff + (r1.x >> 20) * NB + 4);
            const float nm = asf(r1.y);
            fmaC(cA, cB, asf(w1 << 16) * nm, accL);
            fmaC(cA, cB, asf(w1 & 0xFFFF0000u) * nm, accH);
        }
        {
            const float4 cA = *reinterpret_cast<const float4*>(coeff + (r2.x >> 20) * NB);
            const float4 cB = *reinterpret_cast<const float4*>(coeff + (r2.x >> 20) * NB + 4);
            const float nm = asf(r2.y);
            fmaC(cA, cB, asf(w2 << 16) * nm, accL);
            fmaC(cA, cB, asf(w2 & 0xFFFF0000u) * nm, accH);
        }
        {
            const float4 cA = *reinterpret_cast<const float4*>(coeff + (r3.x >> 20) * NB);
            const float4 cB = *reinterpret_cast<const float4*>(coeff + (r3.x >> 20) * NB + 4);
            const float nm = asf(r3.y);
            fmaC(cA, cB, asf(w3 << 16) * nm, accL);
            fmaC(cA, cB, asf(w3 & 0xFFFF0000u) * nm, accH);
        }
    }
    for (; j < j1; j++) {
        const uint2 r0 = rec[j];
        const uint32_t w0 = *reinterpret_cast<const uint32_t*>(
            x + (size_t)(r0.x & 0xFFFFFu) * HDIM + 2 * hl);
        const float4 cA = *reinterpret_cast<const float4*>(coeff + (r0.x >> 20) * NB);
        const float4 cB = *reinterpret_cast<const float4*>(coeff + (r0.x >> 20) * NB + 4);
        const float nm = asf(r0.y);
        fmaC(cA, cB, asf(w0 << 16) * nm, accL);
        fmaC(cA, cB, asf(w0 & 0xFFFF0000u) * nm, accH);
    }
}

// ---------------------------------------------------------------------------
// Fused layer: per 64-node tile, 32 half-waves gather G rows into LDS (2 nodes
// each), then 16 waves do the [64,512]x[512,64] MFMA tile in-place.
// LDS G layout: row (node) stride 512 shorts. Lane hl stores its lo frag at
// 16B-granule hl and hi frag at granule 32+hl, granule index XOR (row&7)
// -> both ds_write_b128 and the GEMM's ds_read_b128 are bank-uniform.
//   k = 16*hl + h*8 + j  lives at granule (h*32 + hl) ^ (row&7), short j.
// GEMM A frag (k = kb*32 + q*8 + j) -> granule ((q&1)*32 + 2kb + (q>>1)) ^ sw.
// G values and MFMA order identical to the previous unfused pipeline.
// ---------------------------------------------------------------------------
__launch_bounds__(1024)
__global__ void fused_hidden_kernel(const uint16_t* __restrict__ x,
                                    const float* __restrict__ coeff,
                                    const float* __restrict__ bases,
                                    const float* __restrict__ bias,
                                    const int* __restrict__ offs,
                                    const uint2* __restrict__ rec,
                                    uint16_t* __restrict__ xout, int nNodes) {
    constexpr int OT = HDIM / 16;       // 4 o-tiles
    __shared__ __align__(16) uint16_t Wf[16 * OT * 64 * 8];   // 64 KB
    __shared__ __align__(16) uint16_t Gs[TILE * KDIM];        // 64 KB

    const int t    = (int)threadIdx.x;
    const int lane = t & 63;
    const int w    = t >> 6;            // 0..15
    const int hw   = t >> 5;            // 0..31
    const int hl   = t & 31;
    const int q    = lane >> 4;
    const int c    = lane & 15;
    const int rt   = w & 3;             // row-tile of this wave
    const int ot   = w >> 2;            // o-tile of this wave

    for (int idx = t; idx < 16 * OT * 64 * 8; idx += 1024) {
        int j    = idx & 7;
        int ln   = (idx >> 3) & 63;
        int rest = idx >> 9;            // kb*OT + ot
        int o_t  = rest & (OT - 1);
        int kb   = rest >> 2;
        int k    = kb * 32 + (ln >> 4) * 8 + j;
        int o    = o_t * 16 + (ln & 15);
        int i    = k >> 3, b = k & 7;
        Wf[idx] = f2bf(bases[(size_t)(b * HDIM + i) * HDIM + o]);
    }
    // (Wf readiness is covered by the barrier between gather and GEMM below)

    const float bv = bias[ot * 16 + c];
    const int rsw  = rt * 16 + c;                 // GEMM A row in tile
    const uint16_t* arow = Gs + rsw * KDIM;
    const int sw   = rsw & 7;

    const int nTiles = (nNodes + TILE - 1) / TILE;
    for (int tile = (int)blockIdx.x; tile < nTiles; tile += (int)gridDim.x) {
        // ---- gather phase: half-wave hw -> tile rows 2hw, 2hw+1
#pragma unroll
        for (int s = 0; s < 2; s++) {
            const int r = hw * 2 + s;
            const int d = tile * TILE + r;
            if (d < nNodes) {
                float accL[NB] = {0.f, 0.f, 0.f, 0.f, 0.f, 0.f, 0.f, 0.f};
                float accH[NB] = {0.f, 0.f, 0.f, 0.f, 0.f, 0.f, 0.f, 0.f};
                gather_node(x, coeff, rec, offs[d], offs[d + 1], hl, accL, accH);
                uint4 lo, hi;
                lo.x = pack2(accL[0], accL[1]); lo.y = pack2(accL[2], accL[3]);
                lo.z = pack2(accL[4], accL[5]); lo.w = pack2(accL[6], accL[7]);
                hi.x = pack2(accH[0], accH[1]); hi.y = pack2(accH[2], accH[3]);
                hi.z = pack2(accH[4], accH[5]); hi.w = pack2(accH[6], accH[7]);
                uint16_t* gp = Gs + r * KDIM;
                *reinterpret_cast<uint4*>(gp + ((hl ^ (r & 7)) * 8))        = lo;
                *reinterpret_cast<uint4*>(gp + (((32 + hl) ^ (r & 7)) * 8)) = hi;
            }
        }
        __syncthreads();

        // ---- GEMM phase: wave (rt,ot) computes 16 rows x 16 cols
        f32x4 acc = {0.f, 0.f, 0.f, 0.f};
#pragma unroll
        for (int kb = 0; kb < 16; kb++) {
            const int g0 = (q & 1) * 32 + 2 * kb + (q >> 1);
            FragU a, b;
            a.u = *reinterpret_cast<const uint4*>(arow + ((g0 ^ sw) * 8));
            b.u = *reinterpret_cast<const uint4*>(Wf + ((kb * OT + ot) * 64 + lane) * 8);
            acc = __builtin_amdgcn_mfma_f32_16x16x32_bf16(a.s, b.s, acc, 0, 0, 0);
        }

        const int nbase = tile * TILE + rt * 16 + q * 4;
#pragma unroll
        for (int ri = 0; ri < 4; ri++) {
            const int node = nbase + ri;
            if (node < nNodes) {
                float v = fmaxf(acc[ri] + bv, 0.f);
                xout[(size_t)node * HDIM + ot * 16 + c] = f2bf(v);
            }
        }
        __syncthreads();   // Gs reused next tile
    }
}

__launch_bounds__(1024)
__global__ void fused_out_kernel(const uint16_t* __restrict__ x,
                                 const float* __restrict__ coeff,
                                 const float* __restrict__ bases,
                                 const float* __restrict__ bias,
                                 const int* __restrict__ offs,
                                 const uint2* __restrict__ rec,
                                 float* __restrict__ out, int nNodes) {
    __shared__ __align__(16) uint16_t Wf[16 * 64 * 8];        // 16 KB
    __shared__ __align__(16) uint16_t Gs[TILE * KDIM];        // 64 KB

    const int t    = (int)threadIdx.x;
    const int lane = t & 63;
    const int w    = t >> 6;
    const int hw   = t >> 5;
    const int hl   = t & 31;
    const int q    = lane >> 4;
    const int c    = lane & 15;

    for (int idx = t; idx < 16 * 64 * 8; idx += 1024) {
        int j  = idx & 7;
        int ln = (idx >> 3) & 63;
        int kb = idx >> 9;
        int k  = kb * 32 + (ln >> 4) * 8 + j;
        int o  = ln & 15;
        int i  = k >> 3, b = k & 7;
        Wf[idx] = f2bf(bases[(size_t)(b * HDIM + i) * ODIM + o]);
    }

    const float bv = bias[c];
    const int rt   = w & 3;
    const int rsw  = rt * 16 + c;
    const uint16_t* arow = Gs + rsw * KDIM;
    const int sw   = rsw & 7;

    const int nTiles = (nNodes + TILE - 1) / TILE;
    for (int tile = (int)blockIdx.x; tile < nTiles; tile += (int)gridDim.x) {
#pragma unroll
        for (int s = 0; s < 2; s++) {
            const int r = hw * 2 + s;
            const int d = tile * TILE + r;
            if (d < nNodes) {
                float accL[NB] = {0.f, 0.f, 0.f, 0.f, 0.f, 0.f, 0.f, 0.f};
                float accH[NB] = {0.f, 0.f, 0.f, 0.f, 0.f, 0.f, 0.f, 0.f};
                gather_node(x, coeff, rec, offs[d], offs[d + 1], hl, accL, accH);
                uint4 lo, hi;
                lo.x = pack2(accL[0], accL[1]); lo.y = pack2(accL[2], accL[3]);
                lo.z = pack2(accL[4], accL[5]); lo.w = pack2(accL[6], accL[7]);
                hi.x = pack2(accH[0], accH[1]); hi.y = pack2(accH[2], accH[3]);
                hi.z = pack2(accH[4], accH[5]); hi.w = pack2(accH[6], accH[7]);
                uint16_t* gp = Gs + r * KDIM;
                *reinterpret_cast<uint4*>(gp + ((hl ^ (r & 7)) * 8))        = lo;
                *reinterpret_cast<uint4*>(gp + (((32 + hl) ^ (r & 7)) * 8)) = hi;
            }
        }
        __syncthreads();

        if (w < 4) {   // OT=1: only 4 waves needed for the GEMM
            f32x4 acc = {0.f, 0.f, 0.f, 0.f};
#pragma unroll
            for (int kb = 0; kb < 16; kb++) {
                const int g0 = (q & 1) * 32 + 2 * kb + (q >> 1);
                FragU a, b;
                a.u = *reinterpret_cast<const uint4*>(arow + ((g0 ^ sw) * 8));
                b.u = *reinterpret_cast<const uint4*>(Wf + ((kb * 64 + lane) * 8));
                acc = __builtin_amdgcn_mfma_f32_16x16x32_bf16(a.s, b.s, acc, 0, 0, 0);
            }
            const int nbase = tile * TILE + rt * 16 + q * 4;
#pragma unroll
            for (int ri = 0; ri < 4; ri++) {
                const int node = nbase + ri;
                if (node < nNodes) out[(size_t)node * ODIM + c] = acc[ri] + bv;
            }
        }
        __syncthreads();
    }
}

extern "C" void kernel_launch(void* const* d_in, const int* in_sizes, int n_in,
                              void* d_out, int out_size, void* d_ws, size_t ws_size,
                              hipStream_t stream) {
    const float* feats  = (const float*)d_in[0];
    const float* coeff0 = (const float*)d_in[1];
    const float* bases0 = (const float*)d_in[2];
    const float* bias0  = (const float*)d_in[3];
    const float* coeff1 = (const float*)d_in[4];
    const float* bases1 = (const float*)d_in[5];
    const float* bias1  = (const float*)d_in[6];
    const float* coeff2 = (const float*)d_in[7];
    const float* bases2 = (const float*)d_in[8];
    const float* bias2  = (const float*)d_in[9];
    const int*   src    = (const int*)d_in[10];
    const int*   dst    = (const int*)d_in[11];
    const int*   etype  = (const int*)d_in[12];
    const float* norm   = (const float*)d_in[13];
    float* out = (float*)d_out;

    char* base = (char*)d_ws;
    // layout: xA 12.8MB | xB 12.8MB | (hole, was G) | offs | cursor | bsum | bbase | rec 8MB
    uint16_t* xA = (uint16_t*)base;
    uint16_t* xB = (uint16_t*)(base + (size_t)NNODES * HDIM * 2);      // +12,800,000
    const size_t OFF_OFFS  = 115200000;
    const size_t OFF_CURS  = OFF_OFFS + 400016;
    const size_t OFF_BSUM  = OFF_CURS + 400016;
    const size_t OFF_BBASE = OFF_BSUM + 1024;
    const size_t OFF_REC   = OFF_BBASE + 1024;                         // 116,002,080
    int*   offs  = (int*)(base + OFF_OFFS);
    int*   curs  = (int*)(base + OFF_CURS);
    int*   bsum  = (int*)(base + OFF_BSUM);
    int*   bbase = (int*)(base + OFF_BBASE);
    uint2* rec   = (uint2*)(base + OFF_REC);

    const int nblk = (NNODES + SCAN_B - 1) / SCAN_B;   // 196 <= 256

    // ---- CSR build (graph identical across layers; built once per call)
    hipLaunchKernelGGL(zero_kernel, dim3(256), dim3(256), 0, stream, curs, NNODES);
    hipLaunchKernelGGL(hist_kernel, dim3(2048), dim3(256), 0, stream, dst, curs, NEDGES);
    hipLaunchKernelGGL(scan_partial_kernel, dim3(nblk), dim3(SCAN_B), 0, stream, curs, bsum, NNODES);
    hipLaunchKernelGGL(scan_base_kernel, dim3(1), dim3(256), 0, stream, bsum, bbase, offs, nblk, NNODES);
    hipLaunchKernelGGL(scan_final_kernel, dim3(nblk), dim3(SCAN_B), 0, stream, curs, bbase, offs, NNODES);
    hipLaunchKernelGGL(scatter_kernel, dim3(2048), dim3(256), 0, stream,
                       src, dst, etype, norm, curs, rec, NEDGES);

    // ---- x0 = bf16(feats)
    hipLaunchKernelGGL(cast_kernel, dim3(2048), dim3(256), 0, stream,
                       feats, xA, NNODES * HDIM / 4);

    // ---- fused layers (no global G round-trip)
    hipLaunchKernelGGL(fused_hidden_kernel, dim3(512), dim3(1024), 0, stream,
                       xA, coeff0, bases0, bias0, offs, rec, xB, NNODES);
    hipLaunchKernelGGL(fused_hidden_kernel, dim3(512), dim3(1024), 0, stream,
                       xB, coeff1, bases1, bias1, offs, rec, xA, NNODES);
    hipLaunchKernelGGL(fused_out_kernel, dim3(512), dim3(1024), 0, stream,
                       xA, coeff2, bases2, bias2, offs, rec, out, NNODES);
}